// Round 1
// baseline (6669.743 us; speedup 1.0000x reference)
//
#include <hip/hip_runtime.h>

#define NB   8
#define NPTS 4096
#define NS   1024
#define NF   64

// ---------------------------------------------------------------------------
// Weight transpose: w (CO,CI) row-major -> wT (CI,CO) so the MLP inner loop
// can fetch 4 consecutive output-channel weights with one uniform s_load_dwordx4.
// ---------------------------------------------------------------------------
struct TArgs {
  const float* src[9];
  int co[9];
  int ci[9];
  int off[9];
};

__global__ __launch_bounds__(256) void transpose_kernel(TArgs a, float* __restrict__ dst) {
  const int id = blockIdx.y;
  const int i  = blockIdx.x * 256 + threadIdx.x;
  const int co = a.co[id], ci = a.ci[id];
  if (i < co * ci) {
    const int o = i / ci;
    const int c = i - o * ci;
    dst[a.off[id] + c * co + o] = a.src[id][i];
  }
}

// ---------------------------------------------------------------------------
// Farthest point sampling. One block per batch. Must match numpy bit-exactly:
// no FMA contraction (use _rn intrinsics), argmax tie-break -> smallest index.
// ---------------------------------------------------------------------------
__global__ __launch_bounds__(256) void fps_kernel(const float* __restrict__ xyz,
                                                  float* __restrict__ new_xyz) {
  const int b   = blockIdx.x;
  const int tid = threadIdx.x;
  __shared__ float sx[NPTS], sy[NPTS], sz[NPTS];
  __shared__ float red_v[4];
  __shared__ int   red_i[4];
  __shared__ int   s_far;

  const float* xb = xyz + (size_t)b * NPTS * 3;
  for (int p = tid; p < NPTS; p += 256) {
    sx[p] = xb[p * 3 + 0];
    sy[p] = xb[p * 3 + 1];
    sz[p] = xb[p * 3 + 2];
  }
  __syncthreads();

  float px[16], py[16], pz[16], dist[16];
#pragma unroll
  for (int r = 0; r < 16; ++r) {
    const int p = tid + 256 * r;
    px[r] = sx[p]; py[r] = sy[p]; pz[r] = sz[p];
    dist[r] = 1e10f;
  }

  int far = 0;
  for (int j = 0; j < NS; ++j) {
    const float cx = sx[far], cy = sy[far], cz = sz[far];
    if (tid == 0) {
      float* o = new_xyz + ((size_t)b * NS + j) * 3;
      o[0] = cx; o[1] = cy; o[2] = cz;
    }
    float bv = -1.0f;
    int   bi = 0x7fffffff;
#pragma unroll
    for (int r = 0; r < 16; ++r) {
      const float dx = __fsub_rn(px[r], cx);
      const float dy = __fsub_rn(py[r], cy);
      const float dz = __fsub_rn(pz[r], cz);
      const float d  = __fadd_rn(__fadd_rn(__fmul_rn(dx, dx), __fmul_rn(dy, dy)),
                                 __fmul_rn(dz, dz));
      const float nd = fminf(dist[r], d);
      dist[r] = nd;
      // ascending r == ascending global index for fixed tid -> strict > keeps first max
      if (nd > bv) { bv = nd; bi = tid + 256 * r; }
    }
    // wave64 butterfly argmax, tie -> smaller index
#pragma unroll
    for (int off = 1; off < 64; off <<= 1) {
      const float ov = __shfl_xor(bv, off);
      const int   oi = __shfl_xor(bi, off);
      if (ov > bv || (ov == bv && oi < bi)) { bv = ov; bi = oi; }
    }
    const int wid = tid >> 6;
    if ((tid & 63) == 0) { red_v[wid] = bv; red_i[wid] = bi; }
    __syncthreads();
    if (tid == 0) {
      float v = red_v[0];
      int   i = red_i[0];
#pragma unroll
      for (int w = 1; w < 4; ++w) {
        const float ov = red_v[w];
        const int   oi = red_i[w];
        if (ov > v || (ov == v && oi < i)) { v = ov; i = oi; }
      }
      s_far = i;
    }
    __syncthreads();
    far = s_far;
  }
}

// ---------------------------------------------------------------------------
// Ball grouping, all three radii in one index-ordered scan.
// One wave per (b,s). "first k indices with sqd <= r^2" == reference's
// where+sort+take(k). Formula replicated exactly: (sn+sp) - 2*dot, _rn ops.
// ---------------------------------------------------------------------------
__global__ __launch_bounds__(64) void group_kernel(
    const float* __restrict__ xyz, const float* __restrict__ new_xyz,
    int* __restrict__ nbr0, int* __restrict__ nbr1, int* __restrict__ nbr2,
    int* __restrict__ cnt0, int* __restrict__ cnt1, int* __restrict__ cnt2) {
  const int bs   = blockIdx.x;
  const int b    = bs >> 10;
  const int lane = threadIdx.x;
  const float r2_0 = (float)(0.1 * 0.1);
  const float r2_1 = (float)(0.2 * 0.2);
  const float r2_2 = (float)(0.4 * 0.4);

  const float cx = new_xyz[bs * 3 + 0];
  const float cy = new_xyz[bs * 3 + 1];
  const float cz = new_xyz[bs * 3 + 2];
  const float sn = __fadd_rn(__fadd_rn(__fmul_rn(cx, cx), __fmul_rn(cy, cy)),
                             __fmul_rn(cz, cz));
  const float* xb = xyz + (size_t)b * NPTS * 3;
  const unsigned long long below = (1ull << lane) - 1ull;

  int c0 = 0, c1 = 0, c2 = 0;
  for (int base = 0; base < NPTS; base += 64) {
    const int p = base + lane;
    const float x = xb[p * 3 + 0], y = xb[p * 3 + 1], z = xb[p * 3 + 2];
    const float sp = __fadd_rn(__fadd_rn(__fmul_rn(x, x), __fmul_rn(y, y)),
                               __fmul_rn(z, z));
    const float dt = __fadd_rn(__fadd_rn(__fmul_rn(cx, x), __fmul_rn(cy, y)),
                               __fmul_rn(cz, z));
    const float sqd = __fsub_rn(__fadd_rn(sn, sp), __fmul_rn(2.0f, dt));
    const bool in0 = (sqd <= r2_0);
    const bool in1 = (sqd <= r2_1);
    const bool in2 = (sqd <= r2_2);
    const unsigned long long m0 = __ballot(in0);
    const unsigned long long m1 = __ballot(in1);
    const unsigned long long m2 = __ballot(in2);
    if (c0 < 16) {
      const int slot = c0 + __popcll(m0 & below);
      if (in0 && slot < 16) nbr0[bs * 16 + slot] = p;
      c0 = min(c0 + __popcll(m0), 16);
    }
    if (c1 < 32) {
      const int slot = c1 + __popcll(m1 & below);
      if (in1 && slot < 32) nbr1[bs * 32 + slot] = p;
      c1 = min(c1 + __popcll(m1), 32);
    }
    if (c2 < 128) {
      const int slot = c2 + __popcll(m2 & below);
      if (in2 && slot < 128) nbr2[bs * 128 + slot] = p;
      c2 = min(c2 + __popcll(m2), 128);
    }
    if (c0 == 16 && c1 == 32 && c2 == 128) break;
  }
  if (lane == 0) {
    cnt0[bs] = c0;
    cnt1[bs] = c1;
    cnt2[bs] = c2;
  }
}

// ---------------------------------------------------------------------------
// Fused gather + 3-layer MLP + max-pool per branch. One wave per (b,s).
// Lane = neighbor (clamped -> uniform control flow -> scalar weight loads).
// Activations in LDS [channel][lane] (lane-private columns -> no barriers,
// 2-way bank aliasing is free). Packed ping-pong: in@0, h1@H1_OFF, h2@0.
// Max-pool over duplicated clamped neighbors == reference's pad-with-first.
// ---------------------------------------------------------------------------
template <int K, int C1, int C2, int C3>
__global__ __launch_bounds__(64) void mlp_kernel(
    const float* __restrict__ xyz, const float* __restrict__ feat,
    const float* __restrict__ new_xyz,
    const int* __restrict__ nbr, const int* __restrict__ cnt_arr,
    const float* __restrict__ w1t, const float* __restrict__ b1,
    const float* __restrict__ w2t, const float* __restrict__ b2,
    const float* __restrict__ w3t, const float* __restrict__ b3,
    float* __restrict__ out, int ch_off) {
  constexpr int CIN    = NF + 3;                    // 67
  constexpr int H1_OFF = (C2 > CIN) ? C2 : CIN;     // h1 region start row
  __shared__ float buf[(H1_OFF + C1) * 64];

  const int bs   = blockIdx.x;
  const int b    = bs >> 10;
  const int lane = threadIdx.x;
  const float cx = new_xyz[bs * 3 + 0];
  const float cy = new_xyz[bs * 3 + 1];
  const float cz = new_xyz[bs * 3 + 2];
  const int cnt = cnt_arr[bs];

  float maxv[C3];
#pragma unroll
  for (int o = 0; o < C3; ++o) maxv[o] = 0.0f;

  for (int t = 0; t < K; t += 64) {
    const int nn  = min(t + lane, cnt - 1);          // clamp: duplicates are free under max
    const int idx = nbr[bs * K + nn];
    // ---- stage input (3 rel coords + 64 features) into rows [0,67) ----
    const float* xp = xyz + ((size_t)b * NPTS + idx) * 3;
    buf[0 * 64 + lane] = xp[0] - cx;
    buf[1 * 64 + lane] = xp[1] - cy;
    buf[2 * 64 + lane] = xp[2] - cz;
    const float4* fp = (const float4*)(feat + ((size_t)b * NPTS + idx) * NF);
#pragma unroll
    for (int c4 = 0; c4 < NF / 4; ++c4) {
      const float4 v = fp[c4];
      buf[(3 + 4 * c4 + 0) * 64 + lane] = v.x;
      buf[(3 + 4 * c4 + 1) * 64 + lane] = v.y;
      buf[(3 + 4 * c4 + 2) * 64 + lane] = v.z;
      buf[(3 + 4 * c4 + 3) * 64 + lane] = v.w;
    }
    // ---- L1: rows[0,CIN) -> rows[H1_OFF, H1_OFF+C1) ----
#pragma unroll
    for (int og = 0; og < C1; og += 4) {
      float a0 = b1[og + 0], a1 = b1[og + 1], a2 = b1[og + 2], a3 = b1[og + 3];
#pragma unroll 4
      for (int c = 0; c < CIN; ++c) {
        const float  x = buf[c * 64 + lane];
        const float4 w = *(const float4*)(w1t + c * C1 + og);
        a0 = fmaf(x, w.x, a0); a1 = fmaf(x, w.y, a1);
        a2 = fmaf(x, w.z, a2); a3 = fmaf(x, w.w, a3);
      }
      buf[(H1_OFF + og + 0) * 64 + lane] = fmaxf(a0, 0.0f);
      buf[(H1_OFF + og + 1) * 64 + lane] = fmaxf(a1, 0.0f);
      buf[(H1_OFF + og + 2) * 64 + lane] = fmaxf(a2, 0.0f);
      buf[(H1_OFF + og + 3) * 64 + lane] = fmaxf(a3, 0.0f);
    }
    // ---- L2: rows[H1_OFF,+C1) -> rows[0,C2) (input region is dead) ----
#pragma unroll
    for (int og = 0; og < C2; og += 4) {
      float a0 = b2[og + 0], a1 = b2[og + 1], a2 = b2[og + 2], a3 = b2[og + 3];
#pragma unroll 4
      for (int c = 0; c < C1; ++c) {
        const float  x = buf[(H1_OFF + c) * 64 + lane];
        const float4 w = *(const float4*)(w2t + c * C2 + og);
        a0 = fmaf(x, w.x, a0); a1 = fmaf(x, w.y, a1);
        a2 = fmaf(x, w.z, a2); a3 = fmaf(x, w.w, a3);
      }
      buf[(og + 0) * 64 + lane] = fmaxf(a0, 0.0f);
      buf[(og + 1) * 64 + lane] = fmaxf(a1, 0.0f);
      buf[(og + 2) * 64 + lane] = fmaxf(a2, 0.0f);
      buf[(og + 3) * 64 + lane] = fmaxf(a3, 0.0f);
    }
    // ---- L3: rows[0,C2) -> registers -> running max ----
#pragma unroll
    for (int og = 0; og < C3; og += 4) {
      float a0 = b3[og + 0], a1 = b3[og + 1], a2 = b3[og + 2], a3 = b3[og + 3];
#pragma unroll 4
      for (int c = 0; c < C2; ++c) {
        const float  x = buf[c * 64 + lane];
        const float4 w = *(const float4*)(w3t + c * C3 + og);
        a0 = fmaf(x, w.x, a0); a1 = fmaf(x, w.y, a1);
        a2 = fmaf(x, w.z, a2); a3 = fmaf(x, w.w, a3);
      }
      maxv[og + 0] = fmaxf(maxv[og + 0], fmaxf(a0, 0.0f));
      maxv[og + 1] = fmaxf(maxv[og + 1], fmaxf(a1, 0.0f));
      maxv[og + 2] = fmaxf(maxv[og + 2], fmaxf(a2, 0.0f));
      maxv[og + 3] = fmaxf(maxv[og + 3], fmaxf(a3, 0.0f));
    }
  }
  // cross-lane max (butterfly -> every lane has the reduced value)
#pragma unroll
  for (int o = 0; o < C3; ++o) {
    float v = maxv[o];
#pragma unroll
    for (int off = 32; off > 0; off >>= 1) v = fmaxf(v, __shfl_xor(v, off));
    maxv[o] = v;
  }
  if (lane == 0) {
    float* op = out + (size_t)bs * 320 + ch_off;
#pragma unroll
    for (int o = 0; o < C3; ++o) op[o] = maxv[o];
  }
}

// ---------------------------------------------------------------------------
// Workspace layout (4-byte units):
//   [0, 44512)            transposed weights (9 matrices, offsets below)
//   [44512, 52704)        cnt0    [52704, 60896) cnt1   [60896, 69088) cnt2
//   [69088, 200160)       nbr0 (8192*16)
//   [200160, 462304)      nbr1 (8192*32)
//   [462304, 1510880)     nbr2 (8192*128)          total ~6.05 MB
// ---------------------------------------------------------------------------
extern "C" void kernel_launch(void* const* d_in, const int* in_sizes, int n_in,
                              void* d_out, int out_size, void* d_ws, size_t ws_size,
                              hipStream_t stream) {
  const float* xyz  = (const float*)d_in[0];
  const float* feat = (const float*)d_in[1];
  float* out      = (float*)d_out;
  float* new_xyz  = out;             // (8,1024,3)  = 24576 floats
  float* feat_out = out + 24576;     // (8,1024,320)

  float* wsf = (float*)d_ws;
  int*   wsi = (int*)d_ws;

  // transposed-weight float offsets
  const int OW[9] = {0, 2144, 3168, 5216, 9504, 13600, 21792, 26080, 32224};
  TArgs ta;
  const int widx[9] = {2, 4, 6, 8, 10, 12, 14, 16, 18};
  const int co[9]   = {32, 32, 64, 64, 64, 128, 64, 96, 128};
  const int ci[9]   = {67, 32, 32, 67, 64, 64, 67, 64, 96};
  for (int i = 0; i < 9; ++i) {
    ta.src[i] = (const float*)d_in[widx[i]];
    ta.co[i]  = co[i];
    ta.ci[i]  = ci[i];
    ta.off[i] = OW[i];
  }
  transpose_kernel<<<dim3(48, 9), 256, 0, stream>>>(ta, wsf);

  fps_kernel<<<NB, 256, 0, stream>>>(xyz, new_xyz);

  int* cnt0 = wsi + 44512;
  int* cnt1 = wsi + 52704;
  int* cnt2 = wsi + 60896;
  int* nbr0 = wsi + 69088;
  int* nbr1 = wsi + 200160;
  int* nbr2 = wsi + 462304;
  group_kernel<<<NB * NS, 64, 0, stream>>>(xyz, new_xyz, nbr0, nbr1, nbr2,
                                           cnt0, cnt1, cnt2);

  mlp_kernel<16, 32, 32, 64><<<NB * NS, 64, 0, stream>>>(
      xyz, feat, new_xyz, nbr0, cnt0,
      wsf + OW[0], (const float*)d_in[3],
      wsf + OW[1], (const float*)d_in[5],
      wsf + OW[2], (const float*)d_in[7],
      feat_out, 0);
  mlp_kernel<32, 64, 64, 128><<<NB * NS, 64, 0, stream>>>(
      xyz, feat, new_xyz, nbr1, cnt1,
      wsf + OW[3], (const float*)d_in[9],
      wsf + OW[4], (const float*)d_in[11],
      wsf + OW[5], (const float*)d_in[13],
      feat_out, 64);
  mlp_kernel<128, 64, 96, 128><<<NB * NS, 64, 0, stream>>>(
      xyz, feat, new_xyz, nbr2, cnt2,
      wsf + OW[6], (const float*)d_in[15],
      wsf + OW[7], (const float*)d_in[17],
      wsf + OW[8], (const float*)d_in[19],
      feat_out, 192);
}

// Round 2
// 1435.444 us; speedup vs baseline: 4.6465x; 4.6465x over previous
//
#include <hip/hip_runtime.h>

#define NB   8
#define NPTS 4096
#define NS   1024
#define NF   64

typedef __bf16 bf16x8 __attribute__((ext_vector_type(8)));
typedef float  f32x4  __attribute__((ext_vector_type(4)));

// ---------------------------------------------------------------------------
// Weight prep: pack fp32 (CO,CI) row-major weights into MFMA B-fragment
// layout for mfma_f32_16x16x32_bf16:
//   frag (ct,kc): lane holds B[k = kc*32 + (lane>>4)*8 + j][n = ct*16 + (lane&15)]
//   flat: dst[off + ((ct*KC + kc)*64 + lane)*8 + j]; zero-pad k >= CI.
// ---------------------------------------------------------------------------
struct WPrep {
  const float* src[9];
  int CO[9], CI[9], KC[9], off[9];
};

__global__ __launch_bounds__(256) void wprep_kernel(WPrep a, __bf16* __restrict__ dst) {
  const int id = blockIdx.y;
  const int t  = blockIdx.x * 256 + threadIdx.x;
  const int CT = a.CO[id] >> 4;
  const int KC = a.KC[id], CI = a.CI[id];
  if (t >= CT * KC * 64) return;
  const int lane = t & 63;
  const int fidx = t >> 6;
  const int kc = fidx % KC;
  const int ct = fidx / KC;
  const int n  = ct * 16 + (lane & 15);
  const int k0 = kc * 32 + (lane >> 4) * 8;
  const float* src = a.src[id];
  __bf16* d = dst + a.off[id] + (size_t)t * 8;
#pragma unroll
  for (int j = 0; j < 8; ++j) {
    const int k = k0 + j;
    d[j] = (__bf16)((k < CI) ? src[n * CI + k] : 0.0f);
  }
}

// ---------------------------------------------------------------------------
// Farthest point sampling. One block per batch. Must match numpy bit-exactly:
// no FMA contraction (_rn intrinsics), argmax tie-break -> smallest index.
// ---------------------------------------------------------------------------
__global__ __launch_bounds__(256) void fps_kernel(const float* __restrict__ xyz,
                                                  float* __restrict__ new_xyz) {
  const int b   = blockIdx.x;
  const int tid = threadIdx.x;
  __shared__ float sx[NPTS], sy[NPTS], sz[NPTS];
  __shared__ float red_v[4];
  __shared__ int   red_i[4];
  __shared__ int   s_far;

  const float* xb = xyz + (size_t)b * NPTS * 3;
  for (int p = tid; p < NPTS; p += 256) {
    sx[p] = xb[p * 3 + 0];
    sy[p] = xb[p * 3 + 1];
    sz[p] = xb[p * 3 + 2];
  }
  __syncthreads();

  float px[16], py[16], pz[16], dist[16];
#pragma unroll
  for (int r = 0; r < 16; ++r) {
    const int p = tid + 256 * r;
    px[r] = sx[p]; py[r] = sy[p]; pz[r] = sz[p];
    dist[r] = 1e10f;
  }

  int far = 0;
  for (int j = 0; j < NS; ++j) {
    const float cx = sx[far], cy = sy[far], cz = sz[far];
    if (tid == 0) {
      float* o = new_xyz + ((size_t)b * NS + j) * 3;
      o[0] = cx; o[1] = cy; o[2] = cz;
    }
    float bv = -1.0f;
    int   bi = 0x7fffffff;
#pragma unroll
    for (int r = 0; r < 16; ++r) {
      const float dx = __fsub_rn(px[r], cx);
      const float dy = __fsub_rn(py[r], cy);
      const float dz = __fsub_rn(pz[r], cz);
      const float d  = __fadd_rn(__fadd_rn(__fmul_rn(dx, dx), __fmul_rn(dy, dy)),
                                 __fmul_rn(dz, dz));
      const float nd = fminf(dist[r], d);
      dist[r] = nd;
      if (nd > bv) { bv = nd; bi = tid + 256 * r; }
    }
#pragma unroll
    for (int off = 1; off < 64; off <<= 1) {
      const float ov = __shfl_xor(bv, off);
      const int   oi = __shfl_xor(bi, off);
      if (ov > bv || (ov == bv && oi < bi)) { bv = ov; bi = oi; }
    }
    const int wid = tid >> 6;
    if ((tid & 63) == 0) { red_v[wid] = bv; red_i[wid] = bi; }
    __syncthreads();
    if (tid == 0) {
      float v = red_v[0];
      int   i = red_i[0];
#pragma unroll
      for (int w = 1; w < 4; ++w) {
        const float ov = red_v[w];
        const int   oi = red_i[w];
        if (ov > v || (ov == v && oi < i)) { v = ov; i = oi; }
      }
      s_far = i;
    }
    __syncthreads();
    far = s_far;
  }
}

// ---------------------------------------------------------------------------
// Ball grouping, all three radii in one index-ordered scan. One wave per (b,s).
// ---------------------------------------------------------------------------
__global__ __launch_bounds__(64) void group_kernel(
    const float* __restrict__ xyz, const float* __restrict__ new_xyz,
    int* __restrict__ nbr0, int* __restrict__ nbr1, int* __restrict__ nbr2,
    int* __restrict__ cnt0, int* __restrict__ cnt1, int* __restrict__ cnt2) {
  const int bs   = blockIdx.x;
  const int b    = bs >> 10;
  const int lane = threadIdx.x;
  const float r2_0 = (float)(0.1 * 0.1);
  const float r2_1 = (float)(0.2 * 0.2);
  const float r2_2 = (float)(0.4 * 0.4);

  const float cx = new_xyz[bs * 3 + 0];
  const float cy = new_xyz[bs * 3 + 1];
  const float cz = new_xyz[bs * 3 + 2];
  const float sn = __fadd_rn(__fadd_rn(__fmul_rn(cx, cx), __fmul_rn(cy, cy)),
                             __fmul_rn(cz, cz));
  const float* xb = xyz + (size_t)b * NPTS * 3;
  const unsigned long long below = (1ull << lane) - 1ull;

  int c0 = 0, c1 = 0, c2 = 0;
  for (int base = 0; base < NPTS; base += 64) {
    const int p = base + lane;
    const float x = xb[p * 3 + 0], y = xb[p * 3 + 1], z = xb[p * 3 + 2];
    const float sp = __fadd_rn(__fadd_rn(__fmul_rn(x, x), __fmul_rn(y, y)),
                               __fmul_rn(z, z));
    const float dt = __fadd_rn(__fadd_rn(__fmul_rn(cx, x), __fmul_rn(cy, y)),
                               __fmul_rn(cz, z));
    const float sqd = __fsub_rn(__fadd_rn(sn, sp), __fmul_rn(2.0f, dt));
    const bool in0 = (sqd <= r2_0);
    const bool in1 = (sqd <= r2_1);
    const bool in2 = (sqd <= r2_2);
    const unsigned long long m0 = __ballot(in0);
    const unsigned long long m1 = __ballot(in1);
    const unsigned long long m2 = __ballot(in2);
    if (c0 < 16) {
      const int slot = c0 + __popcll(m0 & below);
      if (in0 && slot < 16) nbr0[bs * 16 + slot] = p;
      c0 = min(c0 + __popcll(m0), 16);
    }
    if (c1 < 32) {
      const int slot = c1 + __popcll(m1 & below);
      if (in1 && slot < 32) nbr1[bs * 32 + slot] = p;
      c1 = min(c1 + __popcll(m1), 32);
    }
    if (c2 < 128) {
      const int slot = c2 + __popcll(m2 & below);
      if (in2 && slot < 128) nbr2[bs * 128 + slot] = p;
      c2 = min(c2 + __popcll(m2), 128);
    }
    if (c0 == 16 && c1 == 32 && c2 == 128) break;
  }
  if (lane == 0) {
    cnt0[bs] = c0;
    cnt1[bs] = c1;
    cnt2[bs] = c2;
  }
}

// ---------------------------------------------------------------------------
// One layer for one wave: RT row-tiles (16 rows each) x all CO cols, K-chunks
// of 32. A from LDS (rows = this wave's neighbors), B fragments from global
// (pre-packed). Non-last: relu -> bf16 LDS store. Last: per-lane column max.
// ---------------------------------------------------------------------------
template <int RT, int KC, int CO, int SIN, int SOUT, bool LAST>
__device__ __forceinline__ void wave_layer(const __bf16* in, __bf16* outb,
                                           const __bf16* __restrict__ wf,
                                           const float* __restrict__ bias,
                                           int lane, float* colmax) {
  bf16x8 a[RT][KC];
#pragma unroll
  for (int rt = 0; rt < RT; ++rt)
#pragma unroll
    for (int kc = 0; kc < KC; ++kc)
      a[rt][kc] = *(const bf16x8*)(in + (rt * 16 + (lane & 15)) * SIN + kc * 32 +
                                   (lane >> 4) * 8);
#pragma unroll
  for (int ct = 0; ct < CO / 16; ++ct) {
    const float bv = bias[ct * 16 + (lane & 15)];
    bf16x8 bfr[KC];
#pragma unroll
    for (int kc = 0; kc < KC; ++kc)
      bfr[kc] = *(const bf16x8*)(wf + ((size_t)(ct * KC + kc) * 64 + lane) * 8);
    float cm = 0.0f;
#pragma unroll
    for (int rt = 0; rt < RT; ++rt) {
      f32x4 acc = {0.0f, 0.0f, 0.0f, 0.0f};
#pragma unroll
      for (int kc = 0; kc < KC; ++kc)
        acc = __builtin_amdgcn_mfma_f32_16x16x32_bf16(a[rt][kc], bfr[kc], acc, 0, 0, 0);
      if constexpr (!LAST) {
#pragma unroll
        for (int r = 0; r < 4; ++r) {
          const int row = rt * 16 + (lane >> 4) * 4 + r;
          const float v = fmaxf(acc[r] + bv, 0.0f);
          outb[row * SOUT + ct * 16 + (lane & 15)] = (__bf16)v;
        }
      } else {
#pragma unroll
        for (int r = 0; r < 4; ++r) cm = fmaxf(cm, acc[r] + bv);
      }
    }
    if constexpr (LAST) colmax[ct] = fmaxf(colmax[ct], cm);
  }
}

// ---------------------------------------------------------------------------
// Fused gather + 3-layer MFMA MLP + max-pool.
// WPP waves per point, PPB points per block. Row-slices are wave-private
// through gather/L1/L2/L3 (gather threads, L1 rows, L2 rows, L3 rows all
// align to the same wave), so no barriers except the final cross-wave max
// (WPP>1 only; requires SH2==SX so h2 overlays the wave's own X rows).
// LDS row strides C+8 (stride%16==8 elems): 2-way bank alias only, 16B aligned.
// ---------------------------------------------------------------------------
template <int K, int C1, int C2, int C3, int WPP, int PPB>
__global__ __launch_bounds__(64 * WPP * PPB) void mlp_mfma(
    const float* __restrict__ xyz, const float* __restrict__ feat,
    const float* __restrict__ new_xyz,
    const int* __restrict__ nbr, const int* __restrict__ cnt_arr,
    const __bf16* __restrict__ wf1, const float* __restrict__ b1,
    const __bf16* __restrict__ wf2, const float* __restrict__ b2,
    const __bf16* __restrict__ wf3, const float* __restrict__ b3,
    float* __restrict__ out, int ch_off) {
  constexpr int SX  = 104;           // 67 in-ch, zero-pad to 96, stride 104
  constexpr int SH1 = C1 + 8;
  constexpr int SH2 = C2 + 8;
  constexpr int KC1 = 3;
  constexpr int KC2 = C1 / 32;
  constexpr int KC3 = C2 / 32;
  constexpr int PT  = (104 + SH1) * K;   // region0 (X/h2 overlay) + region1 (h1)
  constexpr int MW  = K / WPP;
  constexpr int RT  = MW / 16;
  static_assert(WPP == 1 || SH2 == SX, "h2 overlay must match X rows for WPP>1");
  __shared__ __bf16 lds[PPB * PT];
  __shared__ float  red[(WPP > 1) ? WPP * C3 : 1];

  const int tid  = threadIdx.x;
  const int lane = tid & 63;
  const int wid  = tid >> 6;

  // ---- gather: stage X rows (3 rel coords + 64 feats + zero pad) as bf16 ----
  constexpr int TPN = (64 * WPP) / K;   // threads per neighbor (4, 2, 2)
  constexpr int FPT = NF / TPN;         // features per thread
  {
    const int ln = tid / TPN;
    const int s  = tid - ln * TPN;
    const int lp = ln / K;
    const int n  = ln - lp * K;
    const int p  = blockIdx.x * PPB + lp;
    const int b  = p >> 10;
    const int cnt = cnt_arr[p];
    const int idx = nbr[p * K + min(n, cnt - 1)];
    __bf16* Xr = lds + lp * PT + n * SX;
    const float4* fp4 = (const float4*)(feat + ((size_t)b * NPTS + idx) * NF + s * FPT);
#pragma unroll
    for (int j = 0; j < FPT / 4; ++j) {
      const float4 v = fp4[j];
      Xr[3 + s * FPT + 4 * j + 0] = (__bf16)v.x;
      Xr[3 + s * FPT + 4 * j + 1] = (__bf16)v.y;
      Xr[3 + s * FPT + 4 * j + 2] = (__bf16)v.z;
      Xr[3 + s * FPT + 4 * j + 3] = (__bf16)v.w;
    }
    if (s == 0) {
      const float* xp = xyz + ((size_t)b * NPTS + idx) * 3;
      Xr[0] = (__bf16)(xp[0] - new_xyz[p * 3 + 0]);
      Xr[1] = (__bf16)(xp[1] - new_xyz[p * 3 + 1]);
      Xr[2] = (__bf16)(xp[2] - new_xyz[p * 3 + 2]);
#pragma unroll
      for (int k = 67; k < 96; ++k) Xr[k] = (__bf16)0.0f;
    }
  }

  // ---- per-wave 3-layer pipeline on its own row slice ----
  const int lpg = wid / WPP;
  const int wv  = wid - lpg * WPP;
  const int p   = blockIdx.x * PPB + lpg;
  const __bf16* X  = lds + lpg * PT + wv * MW * SX;
  __bf16*       H1 = lds + lpg * PT + K * 104 + wv * MW * SH1;
  __bf16*       H2 = lds + lpg * PT + wv * MW * SH2;

  float colmax[C3 / 16];
#pragma unroll
  for (int ct = 0; ct < C3 / 16; ++ct) colmax[ct] = 0.0f;

  wave_layer<RT, KC1, C1, SX, SH1, false>(X, H1, wf1, b1, lane, nullptr);
  wave_layer<RT, KC2, C2, SH1, SH2, false>(H1, H2, wf2, b2, lane, nullptr);
  wave_layer<RT, KC3, C3, SH2, 0, true>(H2, nullptr, wf3, b3, lane, colmax);

  // quad-reduce: combine the 4 row-quads of the wave
#pragma unroll
  for (int ct = 0; ct < C3 / 16; ++ct) {
    float v = colmax[ct];
    v = fmaxf(v, __shfl_xor(v, 16));
    v = fmaxf(v, __shfl_xor(v, 32));
    colmax[ct] = v;
  }

  if constexpr (WPP == 1) {
    if (lane < 16) {
      float* op = out + (size_t)p * 320 + ch_off;
#pragma unroll
      for (int ct = 0; ct < C3 / 16; ++ct) op[ct * 16 + lane] = colmax[ct];
    }
  } else {
    if (lane < 16) {
#pragma unroll
      for (int ct = 0; ct < C3 / 16; ++ct)
        red[wv * C3 + ct * 16 + lane] = colmax[ct];
    }
    __syncthreads();
    if (tid < C3) {
      float v = red[tid];
#pragma unroll
      for (int w = 1; w < WPP; ++w) v = fmaxf(v, red[w * C3 + tid]);
      out[(size_t)p * 320 + ch_off + tid] = v;
    }
  }
}

// ---------------------------------------------------------------------------
// Workspace (int units):
//   [0, 24576)        packed bf16 weight fragments (49152 bf16 = 98304 B)
//   [24576, 32768)    cnt0   [32768,40960) cnt1   [40960,49152) cnt2
//   [49152, 180224)   nbr0   [180224,442368) nbr1  [442368,1490944) nbr2
// ---------------------------------------------------------------------------
extern "C" void kernel_launch(void* const* d_in, const int* in_sizes, int n_in,
                              void* d_out, int out_size, void* d_ws, size_t ws_size,
                              hipStream_t stream) {
  const float* xyz  = (const float*)d_in[0];
  const float* feat = (const float*)d_in[1];
  float* out      = (float*)d_out;
  float* new_xyz  = out;
  float* feat_out = out + 24576;

  __bf16* wsb = (__bf16*)d_ws;
  int*    wsi = (int*)d_ws;

  // weight fragment offsets (bf16 elems)
  const int OW[9] = {0, 3072, 4096, 6144, 12288, 16384, 24576, 30720, 36864};
  const int widx[9] = {2, 4, 6, 8, 10, 12, 14, 16, 18};
  const int co[9] = {32, 32, 64, 64, 64, 128, 64, 96, 128};
  const int ci[9] = {67, 32, 32, 67, 64, 64, 67, 64, 96};
  const int kc[9] = {3, 1, 1, 3, 2, 2, 3, 2, 3};
  WPrep wp;
  for (int i = 0; i < 9; ++i) {
    wp.src[i] = (const float*)d_in[widx[i]];
    wp.CO[i] = co[i]; wp.CI[i] = ci[i]; wp.KC[i] = kc[i]; wp.off[i] = OW[i];
  }
  wprep_kernel<<<dim3(6, 9), 256, 0, stream>>>(wp, wsb);

  fps_kernel<<<NB, 256, 0, stream>>>(xyz, new_xyz);

  int* cnt0 = wsi + 24576;
  int* cnt1 = wsi + 32768;
  int* cnt2 = wsi + 40960;
  int* nbr0 = wsi + 49152;
  int* nbr1 = wsi + 180224;
  int* nbr2 = wsi + 442368;
  group_kernel<<<NB * NS, 64, 0, stream>>>(xyz, new_xyz, nbr0, nbr1, nbr2,
                                           cnt0, cnt1, cnt2);

  mlp_mfma<16, 32, 32, 64, 1, 4><<<NB * NS / 4, 256, 0, stream>>>(
      xyz, feat, new_xyz, nbr0, cnt0,
      wsb + OW[0], (const float*)d_in[3],
      wsb + OW[1], (const float*)d_in[5],
      wsb + OW[2], (const float*)d_in[7],
      feat_out, 0);
  mlp_mfma<32, 64, 64, 128, 1, 2><<<NB * NS / 2, 128, 0, stream>>>(
      xyz, feat, new_xyz, nbr1, cnt1,
      wsb + OW[3], (const float*)d_in[9],
      wsb + OW[4], (const float*)d_in[11],
      wsb + OW[5], (const float*)d_in[13],
      feat_out, 64);
  mlp_mfma<128, 64, 96, 128, 4, 1><<<NB * NS, 256, 0, stream>>>(
      xyz, feat, new_xyz, nbr2, cnt2,
      wsb + OW[6], (const float*)d_in[15],
      wsb + OW[7], (const float*)d_in[17],
      wsb + OW[8], (const float*)d_in[19],
      feat_out, 192);
}

// Round 3
// 1017.934 us; speedup vs baseline: 6.5522x; 1.4102x over previous
//
#include <hip/hip_runtime.h>

#define NB   8
#define NPTS 4096
#define NS   1024
#define NF   64

typedef __bf16 bf16x8 __attribute__((ext_vector_type(8)));
typedef float  f32x4  __attribute__((ext_vector_type(4)));

// ---------------------------------------------------------------------------
// Weight prep: pack fp32 (CO,CI) row-major weights into MFMA B-fragment
// layout for mfma_f32_16x16x32_bf16:
//   frag (ct,kc): lane holds B[k = kc*32 + (lane>>4)*8 + j][n = ct*16 + (lane&15)]
//   flat: dst[off + ((ct*KC + kc)*64 + lane)*8 + j]; zero-pad k >= CI.
// ---------------------------------------------------------------------------
struct WPrep {
  const float* src[9];
  int CO[9], CI[9], KC[9], off[9];
};

__global__ __launch_bounds__(256) void wprep_kernel(WPrep a, __bf16* __restrict__ dst) {
  const int id = blockIdx.y;
  const int t  = blockIdx.x * 256 + threadIdx.x;
  const int CT = a.CO[id] >> 4;
  const int KC = a.KC[id], CI = a.CI[id];
  if (t >= CT * KC * 64) return;
  const int lane = t & 63;
  const int fidx = t >> 6;
  const int kc = fidx % KC;
  const int ct = fidx / KC;
  const int n  = ct * 16 + (lane & 15);
  const int k0 = kc * 32 + (lane >> 4) * 8;
  const float* src = a.src[id];
  __bf16* d = dst + a.off[id] + (size_t)t * 8;
#pragma unroll
  for (int j = 0; j < 8; ++j) {
    const int k = k0 + j;
    d[j] = (__bf16)((k < CI) ? src[n * CI + k] : 0.0f);
  }
}

// ---------------------------------------------------------------------------
// Farthest point sampling. One block per batch. Bit-exact vs numpy:
// no FMA contraction (_rn intrinsics), argmax tie-break -> smallest index.
// Per-iteration structure (v2): dist update -> per-lane (bv,bi) -> wave
// butterfly on packed u64 key (bits(bv)<<32 | ~bi; dist>=0 so float bits are
// order-monotone, ~bi makes u64-max tie-break to smaller index) -> lane0
// writes 1 key -> ONE barrier -> all threads redundantly max 4 keys
// (broadcast LDS reads) -> far. Key slots double-buffered by parity so the
// next iteration's write cannot race the current read (single barrier/iter).
// ---------------------------------------------------------------------------
__global__ __launch_bounds__(256) void fps_kernel(const float* __restrict__ xyz,
                                                  float* __restrict__ new_xyz) {
  const int b   = blockIdx.x;
  const int tid = threadIdx.x;
  __shared__ float sx[NPTS], sy[NPTS], sz[NPTS];
  __shared__ unsigned long long keys[8];   // [parity*4 + wave]

  const float* xb = xyz + (size_t)b * NPTS * 3;
  for (int p = tid; p < NPTS; p += 256) {
    sx[p] = xb[p * 3 + 0];
    sy[p] = xb[p * 3 + 1];
    sz[p] = xb[p * 3 + 2];
  }
  __syncthreads();

  float px[16], py[16], pz[16], dist[16];
#pragma unroll
  for (int r = 0; r < 16; ++r) {
    const int p = tid + 256 * r;
    px[r] = sx[p]; py[r] = sy[p]; pz[r] = sz[p];
    dist[r] = 1e10f;
  }

  const int wid = tid >> 6;
  int far = 0;
  for (int j = 0; j < NS; ++j) {
    const float cx = sx[far], cy = sy[far], cz = sz[far];
    if (tid == 0) {
      float* o = new_xyz + ((size_t)b * NS + j) * 3;
      o[0] = cx; o[1] = cy; o[2] = cz;
    }
    float bv = -1.0f;
    int   bi = 0;
#pragma unroll
    for (int r = 0; r < 16; ++r) {
      const float dx = __fsub_rn(px[r], cx);
      const float dy = __fsub_rn(py[r], cy);
      const float dz = __fsub_rn(pz[r], cz);
      const float d  = __fadd_rn(__fadd_rn(__fmul_rn(dx, dx), __fmul_rn(dy, dy)),
                                 __fmul_rn(dz, dz));
      const float nd = fminf(dist[r], d);
      dist[r] = nd;
      // ascending r == ascending global index for fixed tid -> strict > keeps first max
      if (nd > bv) { bv = nd; bi = tid + 256 * r; }
    }
    // pack: bv >= 0 after r=0 (squared dists), so float bits are u32-monotone
    unsigned long long key =
        ((unsigned long long)__float_as_uint(bv) << 32) | (unsigned)(~bi);
#pragma unroll
    for (int off = 1; off < 64; off <<= 1) {
      const unsigned long long ok = __shfl_xor(key, off);
      if (ok > key) key = ok;
    }
    const int par = (j & 1) * 4;
    if ((tid & 63) == 0) keys[par + wid] = key;
    __syncthreads();
    unsigned long long k0 = keys[par + 0];
    const unsigned long long k1 = keys[par + 1];
    const unsigned long long k2 = keys[par + 2];
    const unsigned long long k3 = keys[par + 3];
    if (k1 > k0) k0 = k1;
    if (k2 > k0) k0 = k2;
    if (k3 > k0) k0 = k3;
    far = (int)(~(unsigned)k0) & 0xFFF;
  }
}

// ---------------------------------------------------------------------------
// Ball grouping, all three radii in one index-ordered scan. One wave per (b,s).
// ---------------------------------------------------------------------------
__global__ __launch_bounds__(64) void group_kernel(
    const float* __restrict__ xyz, const float* __restrict__ new_xyz,
    int* __restrict__ nbr0, int* __restrict__ nbr1, int* __restrict__ nbr2,
    int* __restrict__ cnt0, int* __restrict__ cnt1, int* __restrict__ cnt2) {
  const int bs   = blockIdx.x;
  const int b    = bs >> 10;
  const int lane = threadIdx.x;
  const float r2_0 = (float)(0.1 * 0.1);
  const float r2_1 = (float)(0.2 * 0.2);
  const float r2_2 = (float)(0.4 * 0.4);

  const float cx = new_xyz[bs * 3 + 0];
  const float cy = new_xyz[bs * 3 + 1];
  const float cz = new_xyz[bs * 3 + 2];
  const float sn = __fadd_rn(__fadd_rn(__fmul_rn(cx, cx), __fmul_rn(cy, cy)),
                             __fmul_rn(cz, cz));
  const float* xb = xyz + (size_t)b * NPTS * 3;
  const unsigned long long below = (1ull << lane) - 1ull;

  int c0 = 0, c1 = 0, c2 = 0;
  for (int base = 0; base < NPTS; base += 64) {
    const int p = base + lane;
    const float x = xb[p * 3 + 0], y = xb[p * 3 + 1], z = xb[p * 3 + 2];
    const float sp = __fadd_rn(__fadd_rn(__fmul_rn(x, x), __fmul_rn(y, y)),
                               __fmul_rn(z, z));
    const float dt = __fadd_rn(__fadd_rn(__fmul_rn(cx, x), __fmul_rn(cy, y)),
                               __fmul_rn(cz, z));
    const float sqd = __fsub_rn(__fadd_rn(sn, sp), __fmul_rn(2.0f, dt));
    const bool in0 = (sqd <= r2_0);
    const bool in1 = (sqd <= r2_1);
    const bool in2 = (sqd <= r2_2);
    const unsigned long long m0 = __ballot(in0);
    const unsigned long long m1 = __ballot(in1);
    const unsigned long long m2 = __ballot(in2);
    if (c0 < 16) {
      const int slot = c0 + __popcll(m0 & below);
      if (in0 && slot < 16) nbr0[bs * 16 + slot] = p;
      c0 = min(c0 + __popcll(m0), 16);
    }
    if (c1 < 32) {
      const int slot = c1 + __popcll(m1 & below);
      if (in1 && slot < 32) nbr1[bs * 32 + slot] = p;
      c1 = min(c1 + __popcll(m1), 32);
    }
    if (c2 < 128) {
      const int slot = c2 + __popcll(m2 & below);
      if (in2 && slot < 128) nbr2[bs * 128 + slot] = p;
      c2 = min(c2 + __popcll(m2), 128);
    }
    if (c0 == 16 && c1 == 32 && c2 == 128) break;
  }
  if (lane == 0) {
    cnt0[bs] = c0;
    cnt1[bs] = c1;
    cnt2[bs] = c2;
  }
}

// ---------------------------------------------------------------------------
// One layer for one wave: RT row-tiles (16 rows each) x all CO cols, K-chunks
// of 32. A from LDS (rows = this wave's neighbors), B fragments from global
// (pre-packed). Non-last: relu -> bf16 LDS store. Last: per-lane column max.
// ---------------------------------------------------------------------------
template <int RT, int KC, int CO, int SIN, int SOUT, bool LAST>
__device__ __forceinline__ void wave_layer(const __bf16* in, __bf16* outb,
                                           const __bf16* __restrict__ wf,
                                           const float* __restrict__ bias,
                                           int lane, float* colmax) {
  bf16x8 a[RT][KC];
#pragma unroll
  for (int rt = 0; rt < RT; ++rt)
#pragma unroll
    for (int kc = 0; kc < KC; ++kc)
      a[rt][kc] = *(const bf16x8*)(in + (rt * 16 + (lane & 15)) * SIN + kc * 32 +
                                   (lane >> 4) * 8);
#pragma unroll
  for (int ct = 0; ct < CO / 16; ++ct) {
    const float bv = bias[ct * 16 + (lane & 15)];
    bf16x8 bfr[KC];
#pragma unroll
    for (int kc = 0; kc < KC; ++kc)
      bfr[kc] = *(const bf16x8*)(wf + ((size_t)(ct * KC + kc) * 64 + lane) * 8);
    float cm = 0.0f;
#pragma unroll
    for (int rt = 0; rt < RT; ++rt) {
      f32x4 acc = {0.0f, 0.0f, 0.0f, 0.0f};
#pragma unroll
      for (int kc = 0; kc < KC; ++kc)
        acc = __builtin_amdgcn_mfma_f32_16x16x32_bf16(a[rt][kc], bfr[kc], acc, 0, 0, 0);
      if constexpr (!LAST) {
#pragma unroll
        for (int r = 0; r < 4; ++r) {
          const int row = rt * 16 + (lane >> 4) * 4 + r;
          const float v = fmaxf(acc[r] + bv, 0.0f);
          outb[row * SOUT + ct * 16 + (lane & 15)] = (__bf16)v;
        }
      } else {
#pragma unroll
        for (int r = 0; r < 4; ++r) cm = fmaxf(cm, acc[r] + bv);
      }
    }
    if constexpr (LAST) colmax[ct] = fmaxf(colmax[ct], cm);
  }
}

// ---------------------------------------------------------------------------
// Fused gather + 3-layer MFMA MLP + max-pool.
// WPP waves per point, PPB points per block. Row-slices are wave-private
// through gather/L1/L2/L3, so no barriers except the final cross-wave max
// (WPP>1 only; requires SH2==SX so h2 overlays the wave's own X rows).
// LDS row strides C+8 (stride%16==8 elems): 2-way bank alias only, 16B aligned.
// ---------------------------------------------------------------------------
template <int K, int C1, int C2, int C3, int WPP, int PPB>
__global__ __launch_bounds__(64 * WPP * PPB) void mlp_mfma(
    const float* __restrict__ xyz, const float* __restrict__ feat,
    const float* __restrict__ new_xyz,
    const int* __restrict__ nbr, const int* __restrict__ cnt_arr,
    const __bf16* __restrict__ wf1, const float* __restrict__ b1,
    const __bf16* __restrict__ wf2, const float* __restrict__ b2,
    const __bf16* __restrict__ wf3, const float* __restrict__ b3,
    float* __restrict__ out, int ch_off) {
  constexpr int SX  = 104;           // 67 in-ch, zero-pad to 96, stride 104
  constexpr int SH1 = C1 + 8;
  constexpr int SH2 = C2 + 8;
  constexpr int KC1 = 3;
  constexpr int KC2 = C1 / 32;
  constexpr int KC3 = C2 / 32;
  constexpr int PT  = (104 + SH1) * K;   // region0 (X/h2 overlay) + region1 (h1)
  constexpr int MW  = K / WPP;
  constexpr int RT  = MW / 16;
  static_assert(WPP == 1 || SH2 == SX, "h2 overlay must match X rows for WPP>1");
  __shared__ __bf16 lds[PPB * PT];
  __shared__ float  red[(WPP > 1) ? WPP * C3 : 1];

  const int tid  = threadIdx.x;
  const int lane = tid & 63;
  const int wid  = tid >> 6;

  // ---- gather: stage X rows (3 rel coords + 64 feats + zero pad) as bf16 ----
  constexpr int TPN = (64 * WPP) / K;   // threads per neighbor (4, 2, 2)
  constexpr int FPT = NF / TPN;         // features per thread
  {
    const int ln = tid / TPN;
    const int s  = tid - ln * TPN;
    const int lp = ln / K;
    const int n  = ln - lp * K;
    const int p  = blockIdx.x * PPB + lp;
    const int b  = p >> 10;
    const int cnt = cnt_arr[p];
    const int idx = nbr[p * K + min(n, cnt - 1)];
    __bf16* Xr = lds + lp * PT + n * SX;
    const float4* fp4 = (const float4*)(feat + ((size_t)b * NPTS + idx) * NF + s * FPT);
#pragma unroll
    for (int j = 0; j < FPT / 4; ++j) {
      const float4 v = fp4[j];
      Xr[3 + s * FPT + 4 * j + 0] = (__bf16)v.x;
      Xr[3 + s * FPT + 4 * j + 1] = (__bf16)v.y;
      Xr[3 + s * FPT + 4 * j + 2] = (__bf16)v.z;
      Xr[3 + s * FPT + 4 * j + 3] = (__bf16)v.w;
    }
    if (s == 0) {
      const float* xp = xyz + ((size_t)b * NPTS + idx) * 3;
      Xr[0] = (__bf16)(xp[0] - new_xyz[p * 3 + 0]);
      Xr[1] = (__bf16)(xp[1] - new_xyz[p * 3 + 1]);
      Xr[2] = (__bf16)(xp[2] - new_xyz[p * 3 + 2]);
#pragma unroll
      for (int k = 67; k < 96; ++k) Xr[k] = (__bf16)0.0f;
    }
  }

  // ---- per-wave 3-layer pipeline on its own row slice ----
  const int lpg = wid / WPP;
  const int wv  = wid - lpg * WPP;
  const int p   = blockIdx.x * PPB + lpg;
  const __bf16* X  = lds + lpg * PT + wv * MW * SX;
  __bf16*       H1 = lds + lpg * PT + K * 104 + wv * MW * SH1;
  __bf16*       H2 = lds + lpg * PT + wv * MW * SH2;

  float colmax[C3 / 16];
#pragma unroll
  for (int ct = 0; ct < C3 / 16; ++ct) colmax[ct] = 0.0f;

  wave_layer<RT, KC1, C1, SX, SH1, false>(X, H1, wf1, b1, lane, nullptr);
  wave_layer<RT, KC2, C2, SH1, SH2, false>(H1, H2, wf2, b2, lane, nullptr);
  wave_layer<RT, KC3, C3, SH2, 0, true>(H2, nullptr, wf3, b3, lane, colmax);

  // quad-reduce: combine the 4 row-quads of the wave
#pragma unroll
  for (int ct = 0; ct < C3 / 16; ++ct) {
    float v = colmax[ct];
    v = fmaxf(v, __shfl_xor(v, 16));
    v = fmaxf(v, __shfl_xor(v, 32));
    colmax[ct] = v;
  }

  if constexpr (WPP == 1) {
    if (lane < 16) {
      float* op = out + (size_t)p * 320 + ch_off;
#pragma unroll
      for (int ct = 0; ct < C3 / 16; ++ct) op[ct * 16 + lane] = colmax[ct];
    }
  } else {
    if (lane < 16) {
#pragma unroll
      for (int ct = 0; ct < C3 / 16; ++ct)
        red[wv * C3 + ct * 16 + lane] = colmax[ct];
    }
    __syncthreads();
    if (tid < C3) {
      float v = red[tid];
#pragma unroll
      for (int w = 1; w < WPP; ++w) v = fmaxf(v, red[w * C3 + tid]);
      out[(size_t)p * 320 + ch_off + tid] = v;
    }
  }
}

// ---------------------------------------------------------------------------
// Workspace (int units):
//   [0, 24576)        packed bf16 weight fragments (49152 bf16 = 98304 B)
//   [24576, 32768)    cnt0   [32768,40960) cnt1   [40960,49152) cnt2
//   [49152, 180224)   nbr0   [180224,442368) nbr1  [442368,1490944) nbr2
// ---------------------------------------------------------------------------
extern "C" void kernel_launch(void* const* d_in, const int* in_sizes, int n_in,
                              void* d_out, int out_size, void* d_ws, size_t ws_size,
                              hipStream_t stream) {
  const float* xyz  = (const float*)d_in[0];
  const float* feat = (const float*)d_in[1];
  float* out      = (float*)d_out;
  float* new_xyz  = out;
  float* feat_out = out + 24576;

  __bf16* wsb = (__bf16*)d_ws;
  int*    wsi = (int*)d_ws;

  // weight fragment offsets (bf16 elems)
  const int OW[9] = {0, 3072, 4096, 6144, 12288, 16384, 24576, 30720, 36864};
  const int widx[9] = {2, 4, 6, 8, 10, 12, 14, 16, 18};
  const int co[9] = {32, 32, 64, 64, 64, 128, 64, 96, 128};
  const int ci[9] = {67, 32, 32, 67, 64, 64, 67, 64, 96};
  const int kc[9] = {3, 1, 1, 3, 2, 2, 3, 2, 3};
  WPrep wp;
  for (int i = 0; i < 9; ++i) {
    wp.src[i] = (const float*)d_in[widx[i]];
    wp.CO[i] = co[i]; wp.CI[i] = ci[i]; wp.KC[i] = kc[i]; wp.off[i] = OW[i];
  }
  wprep_kernel<<<dim3(6, 9), 256, 0, stream>>>(wp, wsb);

  fps_kernel<<<NB, 256, 0, stream>>>(xyz, new_xyz);

  int* cnt0 = wsi + 24576;
  int* cnt1 = wsi + 32768;
  int* cnt2 = wsi + 40960;
  int* nbr0 = wsi + 49152;
  int* nbr1 = wsi + 180224;
  int* nbr2 = wsi + 442368;
  group_kernel<<<NB * NS, 64, 0, stream>>>(xyz, new_xyz, nbr0, nbr1, nbr2,
                                           cnt0, cnt1, cnt2);

  mlp_mfma<16, 32, 32, 64, 1, 4><<<NB * NS / 4, 256, 0, stream>>>(
      xyz, feat, new_xyz, nbr0, cnt0,
      wsb + OW[0], (const float*)d_in[3],
      wsb + OW[1], (const float*)d_in[5],
      wsb + OW[2], (const float*)d_in[7],
      feat_out, 0);
  mlp_mfma<32, 64, 64, 128, 1, 2><<<NB * NS / 2, 128, 0, stream>>>(
      xyz, feat, new_xyz, nbr1, cnt1,
      wsb + OW[3], (const float*)d_in[9],
      wsb + OW[4], (const float*)d_in[11],
      wsb + OW[5], (const float*)d_in[13],
      feat_out, 64);
  mlp_mfma<128, 64, 96, 128, 4, 1><<<NB * NS, 256, 0, stream>>>(
      xyz, feat, new_xyz, nbr2, cnt2,
      wsb + OW[6], (const float*)d_in[15],
      wsb + OW[7], (const float*)d_in[17],
      wsb + OW[8], (const float*)d_in[19],
      feat_out, 192);
}

// Round 5
// 893.069 us; speedup vs baseline: 7.4683x; 1.1398x over previous
//
#include <hip/hip_runtime.h>

#define NB   8
#define NPTS 4096
#define NS   1024
#define NF   64

typedef __bf16 bf16x8 __attribute__((ext_vector_type(8)));
typedef float  f32x4  __attribute__((ext_vector_type(4)));

// ---------------------------------------------------------------------------
// Weight prep: pack fp32 (CO,CI) row-major weights into MFMA B-fragment
// layout for mfma_f32_16x16x32_bf16:
//   frag (ct,kc): lane holds B[k = kc*32 + (lane>>4)*8 + j][n = ct*16 + (lane&15)]
//   flat: dst[off + ((ct*KC + kc)*64 + lane)*8 + j]; zero-pad k >= CI.
// ---------------------------------------------------------------------------
struct WPrep {
  const float* src[9];
  int CO[9], CI[9], KC[9], off[9];
};

__global__ __launch_bounds__(256) void wprep_kernel(WPrep a, __bf16* __restrict__ dst) {
  const int id = blockIdx.y;
  const int t  = blockIdx.x * 256 + threadIdx.x;
  const int CT = a.CO[id] >> 4;
  const int KC = a.KC[id], CI = a.CI[id];
  if (t >= CT * KC * 64) return;
  const int lane = t & 63;
  const int fidx = t >> 6;
  const int kc = fidx % KC;
  const int ct = fidx / KC;
  const int n  = ct * 16 + (lane & 15);
  const int k0 = kc * 32 + (lane >> 4) * 8;
  const float* src = a.src[id];
  __bf16* d = dst + a.off[id] + (size_t)t * 8;
#pragma unroll
  for (int j = 0; j < 8; ++j) {
    const int k = k0 + j;
    d[j] = (__bf16)((k < CI) ? src[n * CI + k] : 0.0f);
  }
}

// ---------------------------------------------------------------------------
// Farthest point sampling v3. One 512-thread block per batch. Bit-exact vs
// numpy: _rn expression tree, argmax tie-break -> smallest global index.
//   - contiguous mapping: thread t owns indices [8t, 8t+8) -> per-lane first
//     max (strict >) is the lane's smallest index; across lanes, lower lane
//     always means lower indices.
//   - wave max via DPP chain (row_shr 1/2/4/8 + row_bcast15/31, VALU-latency;
//     max is idempotent so full masks are safe; bound_ctrl 0-fill safe since
//     dists >= 0), broadcast with readlane(63).
//   - winner lane = lowest lane with bv == wavemax (ballot+ffs); it writes
//     the packed u64 key (bits(bv)<<32 | ~bi) -- no bpermute anywhere.
//   - ONE barrier/iter; 8-key slots parity double-buffered; every thread
//     redundantly maxes the 8 keys (broadcast LDS reads, conflict-free).
// ---------------------------------------------------------------------------
template <int CTRL>
__device__ __forceinline__ float dpp_fmax_step(float v) {
  const int t = __builtin_amdgcn_update_dpp(0, __float_as_int(v), CTRL, 0xf, 0xf, true);
  return fmaxf(v, __int_as_float(t));
}

__global__ __launch_bounds__(512) void fps_kernel(const float* __restrict__ xyz,
                                                  float* __restrict__ new_xyz) {
  const int b   = blockIdx.x;
  const int tid = threadIdx.x;
  __shared__ float sx[NPTS], sy[NPTS], sz[NPTS];
  __shared__ alignas(16) unsigned long long keys[16];   // [parity*8 + wave]

  const float* xb = xyz + (size_t)b * NPTS * 3;
  for (int p = tid; p < NPTS; p += 512) {
    sx[p] = xb[p * 3 + 0];
    sy[p] = xb[p * 3 + 1];
    sz[p] = xb[p * 3 + 2];
  }
  __syncthreads();

  float px[8], py[8], pz[8], dist[8];
#pragma unroll
  for (int r = 0; r < 8; ++r) {
    const int p = tid * 8 + r;
    px[r] = sx[p]; py[r] = sy[p]; pz[r] = sz[p];
    dist[r] = 1e10f;
  }

  const int wid  = tid >> 6;
  const int lane = tid & 63;
  int far = 0;
  for (int j = 0; j < NS; ++j) {
    const float cx = sx[far], cy = sy[far], cz = sz[far];
    if (tid == 0) {
      float* o = new_xyz + ((size_t)b * NS + j) * 3;
      o[0] = cx; o[1] = cy; o[2] = cz;
    }
    float bv = -1.0f;
    int   bi = 0;
#pragma unroll
    for (int r = 0; r < 8; ++r) {
      const float dx = __fsub_rn(px[r], cx);
      const float dy = __fsub_rn(py[r], cy);
      const float dz = __fsub_rn(pz[r], cz);
      const float d  = __fadd_rn(__fadd_rn(__fmul_rn(dx, dx), __fmul_rn(dy, dy)),
                                 __fmul_rn(dz, dz));
      const float nd = fminf(dist[r], d);
      dist[r] = nd;
      // ascending r == ascending global index -> strict > keeps first max
      if (nd > bv) { bv = nd; bi = tid * 8 + r; }
    }
    // wave max via DPP (VALU-latency chain, no DS unit)
    float v = bv;
    v = dpp_fmax_step<0x111>(v);   // row_shr:1
    v = dpp_fmax_step<0x112>(v);   // row_shr:2
    v = dpp_fmax_step<0x114>(v);   // row_shr:4
    v = dpp_fmax_step<0x118>(v);   // row_shr:8
    v = dpp_fmax_step<0x142>(v);   // row_bcast:15
    v = dpp_fmax_step<0x143>(v);   // row_bcast:31
    const float wmax = __int_as_float(
        __builtin_amdgcn_readlane(__float_as_int(v), 63));
    const unsigned long long cand = __ballot(bv == wmax);
    const int fl = (int)__ffsll((long long)cand) - 1;   // lowest lane = smallest index
    const int par = (j & 1) * 8;
    if (lane == fl)
      keys[par + wid] = ((unsigned long long)__float_as_uint(wmax) << 32) |
                        (unsigned)(~bi);
    __syncthreads();
    const unsigned long long* kk = keys + par;
    unsigned long long k = kk[0];
#pragma unroll
    for (int i = 1; i < 8; ++i) {
      const unsigned long long o = kk[i];
      if (o > k) k = o;
    }
    far = (int)(~(unsigned)k) & 0xFFF;
  }
}

// ---------------------------------------------------------------------------
// Ball grouping, all three radii in one index-ordered scan. One wave per (b,s).
// ---------------------------------------------------------------------------
__global__ __launch_bounds__(64) void group_kernel(
    const float* __restrict__ xyz, const float* __restrict__ new_xyz,
    int* __restrict__ nbr0, int* __restrict__ nbr1, int* __restrict__ nbr2,
    int* __restrict__ cnt0, int* __restrict__ cnt1, int* __restrict__ cnt2) {
  const int bs   = blockIdx.x;
  const int b    = bs >> 10;
  const int lane = threadIdx.x;
  const float r2_0 = (float)(0.1 * 0.1);
  const float r2_1 = (float)(0.2 * 0.2);
  const float r2_2 = (float)(0.4 * 0.4);

  const float cx = new_xyz[bs * 3 + 0];
  const float cy = new_xyz[bs * 3 + 1];
  const float cz = new_xyz[bs * 3 + 2];
  const float sn = __fadd_rn(__fadd_rn(__fmul_rn(cx, cx), __fmul_rn(cy, cy)),
                             __fmul_rn(cz, cz));
  const float* xb = xyz + (size_t)b * NPTS * 3;
  const unsigned long long below = (1ull << lane) - 1ull;

  int c0 = 0, c1 = 0, c2 = 0;
  for (int base = 0; base < NPTS; base += 64) {
    const int p = base + lane;
    const float x = xb[p * 3 + 0], y = xb[p * 3 + 1], z = xb[p * 3 + 2];
    const float sp = __fadd_rn(__fadd_rn(__fmul_rn(x, x), __fmul_rn(y, y)),
                               __fmul_rn(z, z));
    const float dt = __fadd_rn(__fadd_rn(__fmul_rn(cx, x), __fmul_rn(cy, y)),
                               __fmul_rn(cz, z));
    const float sqd = __fsub_rn(__fadd_rn(sn, sp), __fmul_rn(2.0f, dt));
    const bool in0 = (sqd <= r2_0);
    const bool in1 = (sqd <= r2_1);
    const bool in2 = (sqd <= r2_2);
    const unsigned long long m0 = __ballot(in0);
    const unsigned long long m1 = __ballot(in1);
    const unsigned long long m2 = __ballot(in2);
    if (c0 < 16) {
      const int slot = c0 + __popcll(m0 & below);
      if (in0 && slot < 16) nbr0[bs * 16 + slot] = p;
      c0 = min(c0 + __popcll(m0), 16);
    }
    if (c1 < 32) {
      const int slot = c1 + __popcll(m1 & below);
      if (in1 && slot < 32) nbr1[bs * 32 + slot] = p;
      c1 = min(c1 + __popcll(m1), 32);
    }
    if (c2 < 128) {
      const int slot = c2 + __popcll(m2 & below);
      if (in2 && slot < 128) nbr2[bs * 128 + slot] = p;
      c2 = min(c2 + __popcll(m2), 128);
    }
    if (c0 == 16 && c1 == 32 && c2 == 128) break;
  }
  if (lane == 0) {
    cnt0[bs] = c0;
    cnt1[bs] = c1;
    cnt2[bs] = c2;
  }
}

// ---------------------------------------------------------------------------
// One layer for one wave: RT row-tiles (16 rows each) x all CO cols, K-chunks
// of 32. A from LDS (rows = this wave's neighbors), B fragments from global
// (pre-packed). Non-last: relu -> bf16 LDS store. Last: per-lane column max.
// ---------------------------------------------------------------------------
template <int RT, int KC, int CO, int SIN, int SOUT, bool LAST>
__device__ __forceinline__ void wave_layer(const __bf16* in, __bf16* outb,
                                           const __bf16* __restrict__ wf,
                                           const float* __restrict__ bias,
                                           int lane, float* colmax) {
  bf16x8 a[RT][KC];
#pragma unroll
  for (int rt = 0; rt < RT; ++rt)
#pragma unroll
    for (int kc = 0; kc < KC; ++kc)
      a[rt][kc] = *(const bf16x8*)(in + (rt * 16 + (lane & 15)) * SIN + kc * 32 +
                                   (lane >> 4) * 8);
#pragma unroll
  for (int ct = 0; ct < CO / 16; ++ct) {
    const float bv = bias[ct * 16 + (lane & 15)];
    bf16x8 bfr[KC];
#pragma unroll
    for (int kc = 0; kc < KC; ++kc)
      bfr[kc] = *(const bf16x8*)(wf + ((size_t)(ct * KC + kc) * 64 + lane) * 8);
    float cm = 0.0f;
#pragma unroll
    for (int rt = 0; rt < RT; ++rt) {
      f32x4 acc = {0.0f, 0.0f, 0.0f, 0.0f};
#pragma unroll
      for (int kc = 0; kc < KC; ++kc)
        acc = __builtin_amdgcn_mfma_f32_16x16x32_bf16(a[rt][kc], bfr[kc], acc, 0, 0, 0);
      if constexpr (!LAST) {
#pragma unroll
        for (int r = 0; r < 4; ++r) {
          const int row = rt * 16 + (lane >> 4) * 4 + r;
          const float v = fmaxf(acc[r] + bv, 0.0f);
          outb[row * SOUT + ct * 16 + (lane & 15)] = (__bf16)v;
        }
      } else {
#pragma unroll
        for (int r = 0; r < 4; ++r) cm = fmaxf(cm, acc[r] + bv);
      }
    }
    if constexpr (LAST) colmax[ct] = fmaxf(colmax[ct], cm);
  }
}

// ---------------------------------------------------------------------------
// Fused gather + 3-layer MFMA MLP + max-pool.
// WPP waves per point, PPB points per block. Row-slices are wave-private
// through gather/L1/L2/L3, so no barriers except the final cross-wave max
// (WPP>1 only; requires SH2==SX so h2 overlays the wave's own X rows).
// LDS row strides C+8 (stride%16==8 elems): 2-way bank alias only, 16B aligned.
// ---------------------------------------------------------------------------
template <int K, int C1, int C2, int C3, int WPP, int PPB>
__global__ __launch_bounds__(64 * WPP * PPB) void mlp_mfma(
    const float* __restrict__ xyz, const float* __restrict__ feat,
    const float* __restrict__ new_xyz,
    const int* __restrict__ nbr, const int* __restrict__ cnt_arr,
    const __bf16* __restrict__ wf1, const float* __restrict__ b1,
    const __bf16* __restrict__ wf2, const float* __restrict__ b2,
    const __bf16* __restrict__ wf3, const float* __restrict__ b3,
    float* __restrict__ out, int ch_off) {
  constexpr int SX  = 104;           // 67 in-ch, zero-pad to 96, stride 104
  constexpr int SH1 = C1 + 8;
  constexpr int SH2 = C2 + 8;
  constexpr int KC1 = 3;
  constexpr int KC2 = C1 / 32;
  constexpr int KC3 = C2 / 32;
  constexpr int PT  = (104 + SH1) * K;   // region0 (X/h2 overlay) + region1 (h1)
  constexpr int MW  = K / WPP;
  constexpr int RT  = MW / 16;
  static_assert(WPP == 1 || SH2 == SX, "h2 overlay must match X rows for WPP>1");
  __shared__ __bf16 lds[PPB * PT];
  __shared__ float  red[(WPP > 1) ? WPP * C3 : 1];

  const int tid  = threadIdx.x;
  const int lane = tid & 63;
  const int wid  = tid >> 6;

  // ---- gather: stage X rows (3 rel coords + 64 feats + zero pad) as bf16 ----
  constexpr int TPN = (64 * WPP) / K;   // threads per neighbor (4, 2, 2)
  constexpr int FPT = NF / TPN;         // features per thread
  {
    const int ln = tid / TPN;
    const int s  = tid - ln * TPN;
    const int lp = ln / K;
    const int n  = ln - lp * K;
    const int p  = blockIdx.x * PPB + lp;
    const int b  = p >> 10;
    const int cnt = cnt_arr[p];
    const int idx = nbr[p * K + min(n, cnt - 1)];
    __bf16* Xr = lds + lp * PT + n * SX;
    const float4* fp4 = (const float4*)(feat + ((size_t)b * NPTS + idx) * NF + s * FPT);
#pragma unroll
    for (int j = 0; j < FPT / 4; ++j) {
      const float4 v = fp4[j];
      Xr[3 + s * FPT + 4 * j + 0] = (__bf16)v.x;
      Xr[3 + s * FPT + 4 * j + 1] = (__bf16)v.y;
      Xr[3 + s * FPT + 4 * j + 2] = (__bf16)v.z;
      Xr[3 + s * FPT + 4 * j + 3] = (__bf16)v.w;
    }
    if (s == 0) {
      const float* xp = xyz + ((size_t)b * NPTS + idx) * 3;
      Xr[0] = (__bf16)(xp[0] - new_xyz[p * 3 + 0]);
      Xr[1] = (__bf16)(xp[1] - new_xyz[p * 3 + 1]);
      Xr[2] = (__bf16)(xp[2] - new_xyz[p * 3 + 2]);
#pragma unroll
      for (int k = 67; k < 96; ++k) Xr[k] = (__bf16)0.0f;
    }
  }

  // ---- per-wave 3-layer pipeline on its own row slice ----
  const int lpg = wid / WPP;
  const int wv  = wid - lpg * WPP;
  const int p   = blockIdx.x * PPB + lpg;
  const __bf16* X  = lds + lpg * PT + wv * MW * SX;
  __bf16*       H1 = lds + lpg * PT + K * 104 + wv * MW * SH1;
  __bf16*       H2 = lds + lpg * PT + wv * MW * SH2;

  float colmax[C3 / 16];
#pragma unroll
  for (int ct = 0; ct < C3 / 16; ++ct) colmax[ct] = 0.0f;

  wave_layer<RT, KC1, C1, SX, SH1, false>(X, H1, wf1, b1, lane, nullptr);
  wave_layer<RT, KC2, C2, SH1, SH2, false>(H1, H2, wf2, b2, lane, nullptr);
  wave_layer<RT, KC3, C3, SH2, 0, true>(H2, nullptr, wf3, b3, lane, colmax);

  // quad-reduce: combine the 4 row-quads of the wave
#pragma unroll
  for (int ct = 0; ct < C3 / 16; ++ct) {
    float v = colmax[ct];
    v = fmaxf(v, __shfl_xor(v, 16));
    v = fmaxf(v, __shfl_xor(v, 32));
    colmax[ct] = v;
  }

  if constexpr (WPP == 1) {
    if (lane < 16) {
      float* op = out + (size_t)p * 320 + ch_off;
#pragma unroll
      for (int ct = 0; ct < C3 / 16; ++ct) op[ct * 16 + lane] = colmax[ct];
    }
  } else {
    if (lane < 16) {
#pragma unroll
      for (int ct = 0; ct < C3 / 16; ++ct)
        red[wv * C3 + ct * 16 + lane] = colmax[ct];
    }
    __syncthreads();
    if (tid < C3) {
      float v = red[tid];
#pragma unroll
      for (int w = 1; w < WPP; ++w) v = fmaxf(v, red[w * C3 + tid]);
      out[(size_t)p * 320 + ch_off + tid] = v;
    }
  }
}

// ---------------------------------------------------------------------------
// Workspace (int units):
//   [0, 24576)        packed bf16 weight fragments (49152 bf16 = 98304 B)
//   [24576, 32768)    cnt0   [32768,40960) cnt1   [40960,49152) cnt2
//   [49152, 180224)   nbr0   [180224,442368) nbr1  [442368,1490944) nbr2
// ---------------------------------------------------------------------------
extern "C" void kernel_launch(void* const* d_in, const int* in_sizes, int n_in,
                              void* d_out, int out_size, void* d_ws, size_t ws_size,
                              hipStream_t stream) {
  const float* xyz  = (const float*)d_in[0];
  const float* feat = (const float*)d_in[1];
  float* out      = (float*)d_out;
  float* new_xyz  = out;
  float* feat_out = out + 24576;

  __bf16* wsb = (__bf16*)d_ws;
  int*    wsi = (int*)d_ws;

  // weight fragment offsets (bf16 elems)
  const int OW[9] = {0, 3072, 4096, 6144, 12288, 16384, 24576, 30720, 36864};
  const int widx[9] = {2, 4, 6, 8, 10, 12, 14, 16, 18};
  const int co[9] = {32, 32, 64, 64, 64, 128, 64, 96, 128};
  const int ci[9] = {67, 32, 32, 67, 64, 64, 67, 64, 96};
  const int kc[9] = {3, 1, 1, 3, 2, 2, 3, 2, 3};
  WPrep wp;
  for (int i = 0; i < 9; ++i) {
    wp.src[i] = (const float*)d_in[widx[i]];
    wp.CO[i] = co[i]; wp.CI[i] = ci[i]; wp.KC[i] = kc[i]; wp.off[i] = OW[i];
  }
  wprep_kernel<<<dim3(6, 9), 256, 0, stream>>>(wp, wsb);

  fps_kernel<<<NB, 512, 0, stream>>>(xyz, new_xyz);

  int* cnt0 = wsi + 24576;
  int* cnt1 = wsi + 32768;
  int* cnt2 = wsi + 40960;
  int* nbr0 = wsi + 49152;
  int* nbr1 = wsi + 180224;
  int* nbr2 = wsi + 442368;
  group_kernel<<<NB * NS, 64, 0, stream>>>(xyz, new_xyz, nbr0, nbr1, nbr2,
                                           cnt0, cnt1, cnt2);

  mlp_mfma<16, 32, 32, 64, 1, 4><<<NB * NS / 4, 256, 0, stream>>>(
      xyz, feat, new_xyz, nbr0, cnt0,
      wsb + OW[0], (const float*)d_in[3],
      wsb + OW[1], (const float*)d_in[5],
      wsb + OW[2], (const float*)d_in[7],
      feat_out, 0);
  mlp_mfma<32, 64, 64, 128, 1, 2><<<NB * NS / 2, 128, 0, stream>>>(
      xyz, feat, new_xyz, nbr1, cnt1,
      wsb + OW[3], (const float*)d_in[9],
      wsb + OW[4], (const float*)d_in[11],
      wsb + OW[5], (const float*)d_in[13],
      feat_out, 64);
  mlp_mfma<128, 64, 96, 128, 4, 1><<<NB * NS, 256, 0, stream>>>(
      xyz, feat, new_xyz, nbr2, cnt2,
      wsb + OW[6], (const float*)d_in[15],
      wsb + OW[7], (const float*)d_in[17],
      wsb + OW[8], (const float*)d_in[19],
      feat_out, 192);
}

// Round 6
// 866.253 us; speedup vs baseline: 7.6995x; 1.0310x over previous
//
#include <hip/hip_runtime.h>

#define NB   8
#define NPTS 4096
#define NS   1024
#define NF   64

typedef __bf16 bf16x8 __attribute__((ext_vector_type(8)));
typedef float  f32x4  __attribute__((ext_vector_type(4)));
typedef unsigned long long ullx2 __attribute__((ext_vector_type(2)));

// ---------------------------------------------------------------------------
// Weight prep: pack fp32 (CO,CI) row-major weights into MFMA B-fragment
// layout for mfma_f32_16x16x32_bf16 (see wave_layer).
// ---------------------------------------------------------------------------
struct WPrep {
  const float* src[9];
  int CO[9], CI[9], KC[9], off[9];
};

__global__ __launch_bounds__(256) void wprep_kernel(WPrep a, __bf16* __restrict__ dst) {
  const int id = blockIdx.y;
  const int t  = blockIdx.x * 256 + threadIdx.x;
  const int CT = a.CO[id] >> 4;
  const int KC = a.KC[id], CI = a.CI[id];
  if (t >= CT * KC * 64) return;
  const int lane = t & 63;
  const int fidx = t >> 6;
  const int kc = fidx % KC;
  const int ct = fidx / KC;
  const int n  = ct * 16 + (lane & 15);
  const int k0 = kc * 32 + (lane >> 4) * 8;
  const float* src = a.src[id];
  __bf16* d = dst + a.off[id] + (size_t)t * 8;
#pragma unroll
  for (int j = 0; j < 8; ++j) {
    const int k = k0 + j;
    d[j] = (__bf16)((k < CI) ? src[n * CI + k] : 0.0f);
  }
}

// ---------------------------------------------------------------------------
// Point prep: (x,y,z) -> (x,y,z,|p|^2) float4, norm with the exact _rn chain
// group_kernel previously used (bit-identical sqd downstream).
// ---------------------------------------------------------------------------
__global__ __launch_bounds__(256) void pts_prep(const float* __restrict__ xyz,
                                                float4* __restrict__ pts4) {
  const int i = blockIdx.x * 256 + threadIdx.x;
  if (i >= NB * NPTS) return;
  const float x = xyz[i * 3 + 0], y = xyz[i * 3 + 1], z = xyz[i * 3 + 2];
  const float sp = __fadd_rn(__fadd_rn(__fmul_rn(x, x), __fmul_rn(y, y)),
                             __fmul_rn(z, z));
  pts4[i] = make_float4(x, y, z, sp);
}

// ---------------------------------------------------------------------------
// Farthest point sampling v4. One 256-thread block (4 waves, 1 wave/SIMD) per
// batch. Bit-exact vs numpy: _rn expression tree, first-max tie-breaking.
//   - contiguous mapping: thread t owns indices [16t, 16t+16).
//   - wave max via DPP chain; winner lane via ballot+ffs writes packed u64
//     key (bits(bv)<<32 | ~bi).
//   - ONE barrier/iter; 4-key slots parity double-buffered; scan via two
//     explicit b128 loads (no serialized per-element read+wait).
// ---------------------------------------------------------------------------
template <int CTRL>
__device__ __forceinline__ float dpp_fmax_step(float v) {
  const int t = __builtin_amdgcn_update_dpp(0, __float_as_int(v), CTRL, 0xf, 0xf, true);
  return fmaxf(v, __int_as_float(t));
}

__global__ __launch_bounds__(256) void fps_kernel(const float* __restrict__ xyz,
                                                  float* __restrict__ new_xyz) {
  const int b   = blockIdx.x;
  const int tid = threadIdx.x;
  __shared__ float sx[NPTS], sy[NPTS], sz[NPTS];
  __shared__ alignas(16) unsigned long long keys[8];   // [parity*4 + wave]

  const float* xb = xyz + (size_t)b * NPTS * 3;
  for (int p = tid; p < NPTS; p += 256) {
    sx[p] = xb[p * 3 + 0];
    sy[p] = xb[p * 3 + 1];
    sz[p] = xb[p * 3 + 2];
  }
  __syncthreads();

  float px[16], py[16], pz[16], dist[16];
#pragma unroll
  for (int r = 0; r < 16; ++r) {
    const int p = tid * 16 + r;                 // contiguous: lane order = index order
    px[r] = sx[p]; py[r] = sy[p]; pz[r] = sz[p];
    dist[r] = 1e10f;
  }

  const int wid  = tid >> 6;
  const int lane = tid & 63;
  int far = 0;
  for (int j = 0; j < NS; ++j) {
    const float cx = sx[far], cy = sy[far], cz = sz[far];
    if (tid == 0) {
      float* o = new_xyz + ((size_t)b * NS + j) * 3;
      o[0] = cx; o[1] = cy; o[2] = cz;
    }
    float bv = -1.0f;
    int   bi = 0;
#pragma unroll
    for (int r = 0; r < 16; ++r) {
      const float dx = __fsub_rn(px[r], cx);
      const float dy = __fsub_rn(py[r], cy);
      const float dz = __fsub_rn(pz[r], cz);
      const float d  = __fadd_rn(__fadd_rn(__fmul_rn(dx, dx), __fmul_rn(dy, dy)),
                                 __fmul_rn(dz, dz));
      const float nd = fminf(dist[r], d);
      dist[r] = nd;
      // ascending r == ascending global index -> strict > keeps first max
      if (nd > bv) { bv = nd; bi = tid * 16 + r; }
    }
    // wave max via DPP (VALU-latency chain, no DS unit)
    float v = bv;
    v = dpp_fmax_step<0x111>(v);   // row_shr:1
    v = dpp_fmax_step<0x112>(v);   // row_shr:2
    v = dpp_fmax_step<0x114>(v);   // row_shr:4
    v = dpp_fmax_step<0x118>(v);   // row_shr:8
    v = dpp_fmax_step<0x142>(v);   // row_bcast:15
    v = dpp_fmax_step<0x143>(v);   // row_bcast:31
    const float wmax = __int_as_float(
        __builtin_amdgcn_readlane(__float_as_int(v), 63));
    const unsigned long long cand = __ballot(bv == wmax);
    const int fl = (int)__ffsll((long long)cand) - 1;   // lowest lane = smallest index
    const int par = (j & 1) * 4;
    if (lane == fl)
      keys[par + wid] = ((unsigned long long)__float_as_uint(wmax) << 32) |
                        (unsigned)(~bi);
    __syncthreads();
    // flat 4-key scan: two b128 loads, 3 u64 maxes (no per-element waits)
    const ullx2 ka = *(const ullx2*)(keys + par);
    const ullx2 kb = *(const ullx2*)(keys + par + 2);
    unsigned long long k = ka.x;
    if (ka.y > k) k = ka.y;
    if (kb.x > k) k = kb.x;
    if (kb.y > k) k = kb.y;
    far = (int)(~(unsigned)k) & 0xFFF;
  }
}

// ---------------------------------------------------------------------------
// Ball grouping, all three radii in one index-ordered scan. One wave per (b,s).
// Reads precomputed (x,y,z,|p|^2) float4: one coalesced 16B load per point.
// ---------------------------------------------------------------------------
__global__ __launch_bounds__(64) void group_kernel(
    const float4* __restrict__ pts4, const float* __restrict__ new_xyz,
    int* __restrict__ nbr0, int* __restrict__ nbr1, int* __restrict__ nbr2,
    int* __restrict__ cnt0, int* __restrict__ cnt1, int* __restrict__ cnt2) {
  const int bs   = blockIdx.x;
  const int b    = bs >> 10;
  const int lane = threadIdx.x;
  const float r2_0 = (float)(0.1 * 0.1);
  const float r2_1 = (float)(0.2 * 0.2);
  const float r2_2 = (float)(0.4 * 0.4);

  const float cx = new_xyz[bs * 3 + 0];
  const float cy = new_xyz[bs * 3 + 1];
  const float cz = new_xyz[bs * 3 + 2];
  const float sn = __fadd_rn(__fadd_rn(__fmul_rn(cx, cx), __fmul_rn(cy, cy)),
                             __fmul_rn(cz, cz));
  const float4* pb = pts4 + (size_t)b * NPTS;
  const unsigned long long below = (1ull << lane) - 1ull;

  int c0 = 0, c1 = 0, c2 = 0;
  for (int base = 0; base < NPTS; base += 64) {
    const int p = base + lane;
    const float4 P = pb[p];
    const float dt = __fadd_rn(__fadd_rn(__fmul_rn(cx, P.x), __fmul_rn(cy, P.y)),
                               __fmul_rn(cz, P.z));
    const float sqd = __fsub_rn(__fadd_rn(sn, P.w), __fmul_rn(2.0f, dt));
    const bool in0 = (sqd <= r2_0);
    const bool in1 = (sqd <= r2_1);
    const bool in2 = (sqd <= r2_2);
    const unsigned long long m0 = __ballot(in0);
    const unsigned long long m1 = __ballot(in1);
    const unsigned long long m2 = __ballot(in2);
    if (c0 < 16) {
      const int slot = c0 + __popcll(m0 & below);
      if (in0 && slot < 16) nbr0[bs * 16 + slot] = p;
      c0 = min(c0 + __popcll(m0), 16);
    }
    if (c1 < 32) {
      const int slot = c1 + __popcll(m1 & below);
      if (in1 && slot < 32) nbr1[bs * 32 + slot] = p;
      c1 = min(c1 + __popcll(m1), 32);
    }
    if (c2 < 128) {
      const int slot = c2 + __popcll(m2 & below);
      if (in2 && slot < 128) nbr2[bs * 128 + slot] = p;
      c2 = min(c2 + __popcll(m2), 128);
    }
    if (c0 == 16 && c1 == 32 && c2 == 128) break;
  }
  if (lane == 0) {
    cnt0[bs] = c0;
    cnt1[bs] = c1;
    cnt2[bs] = c2;
  }
}

// ---------------------------------------------------------------------------
// One layer for one wave: RT row-tiles (16 rows each) x all CO cols, K-chunks
// of 32. A from LDS (rows = this wave's neighbors), B fragments from global
// (pre-packed). Non-last: relu -> bf16 LDS store. Last: per-lane column max.
// ---------------------------------------------------------------------------
template <int RT, int KC, int CO, int SIN, int SOUT, bool LAST>
__device__ __forceinline__ void wave_layer(const __bf16* in, __bf16* outb,
                                           const __bf16* __restrict__ wf,
                                           const float* __restrict__ bias,
                                           int lane, float* colmax) {
  bf16x8 a[RT][KC];
#pragma unroll
  for (int rt = 0; rt < RT; ++rt)
#pragma unroll
    for (int kc = 0; kc < KC; ++kc)
      a[rt][kc] = *(const bf16x8*)(in + (rt * 16 + (lane & 15)) * SIN + kc * 32 +
                                   (lane >> 4) * 8);
#pragma unroll
  for (int ct = 0; ct < CO / 16; ++ct) {
    const float bv = bias[ct * 16 + (lane & 15)];
    bf16x8 bfr[KC];
#pragma unroll
    for (int kc = 0; kc < KC; ++kc)
      bfr[kc] = *(const bf16x8*)(wf + ((size_t)(ct * KC + kc) * 64 + lane) * 8);
    float cm = 0.0f;
#pragma unroll
    for (int rt = 0; rt < RT; ++rt) {
      f32x4 acc = {0.0f, 0.0f, 0.0f, 0.0f};
#pragma unroll
      for (int kc = 0; kc < KC; ++kc)
        acc = __builtin_amdgcn_mfma_f32_16x16x32_bf16(a[rt][kc], bfr[kc], acc, 0, 0, 0);
      if constexpr (!LAST) {
#pragma unroll
        for (int r = 0; r < 4; ++r) {
          const int row = rt * 16 + (lane >> 4) * 4 + r;
          const float v = fmaxf(acc[r] + bv, 0.0f);
          outb[row * SOUT + ct * 16 + (lane & 15)] = (__bf16)v;
        }
      } else {
#pragma unroll
        for (int r = 0; r < 4; ++r) cm = fmaxf(cm, acc[r] + bv);
      }
    }
    if constexpr (LAST) colmax[ct] = fmaxf(colmax[ct], cm);
  }
}

// ---------------------------------------------------------------------------
// Fused gather + 3-layer MFMA MLP + max-pool.
// WPP waves per point, PPB points per block. Row-slices are wave-private
// through gather/L1/L2/L3, so no barriers except the final cross-wave max
// (WPP>1 only; requires SH2==SX so h2 overlays the wave's own X rows).
// LDS row strides C+8 (stride%16==8 elems): 2-way bank alias only, 16B aligned.
// ---------------------------------------------------------------------------
template <int K, int C1, int C2, int C3, int WPP, int PPB>
__global__ __launch_bounds__(64 * WPP * PPB) void mlp_mfma(
    const float4* __restrict__ pts4, const float* __restrict__ feat,
    const float* __restrict__ new_xyz,
    const int* __restrict__ nbr, const int* __restrict__ cnt_arr,
    const __bf16* __restrict__ wf1, const float* __restrict__ b1,
    const __bf16* __restrict__ wf2, const float* __restrict__ b2,
    const __bf16* __restrict__ wf3, const float* __restrict__ b3,
    float* __restrict__ out, int ch_off) {
  constexpr int SX  = 104;           // 67 in-ch, zero-pad to 96, stride 104
  constexpr int SH1 = C1 + 8;
  constexpr int SH2 = C2 + 8;
  constexpr int KC1 = 3;
  constexpr int KC2 = C1 / 32;
  constexpr int KC3 = C2 / 32;
  constexpr int PT  = (104 + SH1) * K;   // region0 (X/h2 overlay) + region1 (h1)
  constexpr int MW  = K / WPP;
  constexpr int RT  = MW / 16;
  static_assert(WPP == 1 || SH2 == SX, "h2 overlay must match X rows for WPP>1");
  __shared__ __bf16 lds[PPB * PT];
  __shared__ float  red[(WPP > 1) ? WPP * C3 : 1];

  const int tid  = threadIdx.x;
  const int lane = tid & 63;
  const int wid  = tid >> 6;

  // ---- gather: stage X rows (3 rel coords + 64 feats + zero pad) as bf16 ----
  constexpr int TPN = (64 * WPP) / K;   // threads per neighbor (4, 2, 2)
  constexpr int FPT = NF / TPN;         // features per thread
  {
    const int ln = tid / TPN;
    const int s  = tid - ln * TPN;
    const int lp = ln / K;
    const int n  = ln - lp * K;
    const int p  = blockIdx.x * PPB + lp;
    const int b  = p >> 10;
    const int cnt = cnt_arr[p];
    const int idx = nbr[p * K + min(n, cnt - 1)];
    __bf16* Xr = lds + lp * PT + n * SX;
    const float4* fp4 = (const float4*)(feat + ((size_t)b * NPTS + idx) * NF + s * FPT);
#pragma unroll
    for (int j = 0; j < FPT / 4; ++j) {
      const float4 v = fp4[j];
      Xr[3 + s * FPT + 4 * j + 0] = (__bf16)v.x;
      Xr[3 + s * FPT + 4 * j + 1] = (__bf16)v.y;
      Xr[3 + s * FPT + 4 * j + 2] = (__bf16)v.z;
      Xr[3 + s * FPT + 4 * j + 3] = (__bf16)v.w;
    }
    if (s == 0) {
      const float4 P = pts4[(size_t)b * NPTS + idx];
      Xr[0] = (__bf16)(P.x - new_xyz[p * 3 + 0]);
      Xr[1] = (__bf16)(P.y - new_xyz[p * 3 + 1]);
      Xr[2] = (__bf16)(P.z - new_xyz[p * 3 + 2]);
#pragma unroll
      for (int k = 67; k < 96; ++k) Xr[k] = (__bf16)0.0f;
    }
  }

  // ---- per-wave 3-layer pipeline on its own row slice ----
  const int lpg = wid / WPP;
  const int wv  = wid - lpg * WPP;
  const int p   = blockIdx.x * PPB + lpg;
  const __bf16* X  = lds + lpg * PT + wv * MW * SX;
  __bf16*       H1 = lds + lpg * PT + K * 104 + wv * MW * SH1;
  __bf16*       H2 = lds + lpg * PT + wv * MW * SH2;

  float colmax[C3 / 16];
#pragma unroll
  for (int ct = 0; ct < C3 / 16; ++ct) colmax[ct] = 0.0f;

  wave_layer<RT, KC1, C1, SX, SH1, false>(X, H1, wf1, b1, lane, nullptr);
  wave_layer<RT, KC2, C2, SH1, SH2, false>(H1, H2, wf2, b2, lane, nullptr);
  wave_layer<RT, KC3, C3, SH2, 0, true>(H2, nullptr, wf3, b3, lane, colmax);

  // quad-reduce: combine the 4 row-quads of the wave
#pragma unroll
  for (int ct = 0; ct < C3 / 16; ++ct) {
    float v = colmax[ct];
    v = fmaxf(v, __shfl_xor(v, 16));
    v = fmaxf(v, __shfl_xor(v, 32));
    colmax[ct] = v;
  }

  if constexpr (WPP == 1) {
    if (lane < 16) {
      float* op = out + (size_t)p * 320 + ch_off;
#pragma unroll
      for (int ct = 0; ct < C3 / 16; ++ct) op[ct * 16 + lane] = colmax[ct];
    }
  } else {
    if (lane < 16) {
#pragma unroll
      for (int ct = 0; ct < C3 / 16; ++ct)
        red[wv * C3 + ct * 16 + lane] = colmax[ct];
    }
    __syncthreads();
    if (tid < C3) {
      float v = red[tid];
#pragma unroll
      for (int w = 1; w < WPP; ++w) v = fmaxf(v, red[w * C3 + tid]);
      out[(size_t)p * 320 + ch_off + tid] = v;
    }
  }
}

// ---------------------------------------------------------------------------
// Workspace (int units):
//   [0, 24576)          packed bf16 weight fragments (49152 bf16 = 98304 B)
//   [24576, 32768)      cnt0   [32768,40960) cnt1   [40960,49152) cnt2
//   [49152, 180224)     nbr0   [180224,442368) nbr1  [442368,1490944) nbr2
//   [1490944, 1622016)  pts4 (32768 x float4)        total ~6.49 MB
// ---------------------------------------------------------------------------
extern "C" void kernel_launch(void* const* d_in, const int* in_sizes, int n_in,
                              void* d_out, int out_size, void* d_ws, size_t ws_size,
                              hipStream_t stream) {
  const float* xyz  = (const float*)d_in[0];
  const float* feat = (const float*)d_in[1];
  float* out      = (float*)d_out;
  float* new_xyz  = out;
  float* feat_out = out + 24576;

  __bf16* wsb = (__bf16*)d_ws;
  int*    wsi = (int*)d_ws;

  // weight fragment offsets (bf16 elems)
  const int OW[9] = {0, 3072, 4096, 6144, 12288, 16384, 24576, 30720, 36864};
  const int widx[9] = {2, 4, 6, 8, 10, 12, 14, 16, 18};
  const int co[9] = {32, 32, 64, 64, 64, 128, 64, 96, 128};
  const int ci[9] = {67, 32, 32, 67, 64, 64, 67, 64, 96};
  const int kc[9] = {3, 1, 1, 3, 2, 2, 3, 2, 3};
  WPrep wp;
  for (int i = 0; i < 9; ++i) {
    wp.src[i] = (const float*)d_in[widx[i]];
    wp.CO[i] = co[i]; wp.CI[i] = ci[i]; wp.KC[i] = kc[i]; wp.off[i] = OW[i];
  }
  wprep_kernel<<<dim3(6, 9), 256, 0, stream>>>(wp, wsb);

  float4* pts4 = (float4*)(wsi + 1490944);
  pts_prep<<<(NB * NPTS + 255) / 256, 256, 0, stream>>>(xyz, pts4);

  fps_kernel<<<NB, 256, 0, stream>>>(xyz, new_xyz);

  int* cnt0 = wsi + 24576;
  int* cnt1 = wsi + 32768;
  int* cnt2 = wsi + 40960;
  int* nbr0 = wsi + 49152;
  int* nbr1 = wsi + 180224;
  int* nbr2 = wsi + 442368;
  group_kernel<<<NB * NS, 64, 0, stream>>>(pts4, new_xyz, nbr0, nbr1, nbr2,
                                           cnt0, cnt1, cnt2);

  mlp_mfma<16, 32, 32, 64, 1, 4><<<NB * NS / 4, 256, 0, stream>>>(
      pts4, feat, new_xyz, nbr0, cnt0,
      wsb + OW[0], (const float*)d_in[3],
      wsb + OW[1], (const float*)d_in[5],
      wsb + OW[2], (const float*)d_in[7],
      feat_out, 0);
  mlp_mfma<32, 64, 64, 128, 1, 2><<<NB * NS / 2, 128, 0, stream>>>(
      pts4, feat, new_xyz, nbr1, cnt1,
      wsb + OW[3], (const float*)d_in[9],
      wsb + OW[4], (const float*)d_in[11],
      wsb + OW[5], (const float*)d_in[13],
      feat_out, 64);
  mlp_mfma<128, 64, 96, 128, 4, 1><<<NB * NS, 256, 0, stream>>>(
      pts4, feat, new_xyz, nbr2, cnt2,
      wsb + OW[6], (const float*)d_in[15],
      wsb + OW[7], (const float*)d_in[17],
      wsb + OW[8], (const float*)d_in[19],
      feat_out, 192);
}